// Round 1
// baseline (175.750 us; speedup 1.0000x reference)
//
#include <hip/hip_runtime.h>
#include <cstdint>
#include <cstddef>

#define NB 16
#define NC 256
#define NN 4096
#define ND 256

typedef unsigned short u16;
typedef unsigned int u32;

typedef __attribute__((ext_vector_type(8))) short short8;
typedef __attribute__((ext_vector_type(4))) float f32x4;

__device__ __forceinline__ u16 f2bf(float f) {
  union { float f; u32 u; } v; v.f = f;
  u32 r = v.u + 0x7FFFu + ((v.u >> 16) & 1u);
  return (u16)(r >> 16);
}

// ---------------------------------------------------------------------------
// Kernel 1: cast x (fp32, [b][c][n]) -> xbT (bf16, [b][n][c]) via LDS tile
// transpose. 64x64 tiles, pad stride 68 to dodge bank conflicts.
// ---------------------------------------------------------------------------
__global__ __launch_bounds__(256) void k_cast_transpose(const float* __restrict__ x,
                                                        u16* __restrict__ xbT) {
  __shared__ __align__(16) u16 tile[64 * 68];
  const int t = threadIdx.x;
  const int b = blockIdx.z, c0 = blockIdx.y * 64, n0 = blockIdx.x * 64;
  const float* xb = x + (size_t)(b * NC + c0) * NN + n0;
#pragma unroll
  for (int i = 0; i < 4; ++i) {
    int e = t + i * 256;        // 0..1023
    int cl = e >> 4;            // 0..63
    int nl = (e & 15) * 4;      // 0..60
    float4 v = *(const float4*)(xb + (size_t)cl * NN + nl);
    tile[(nl + 0) * 68 + cl] = f2bf(v.x);
    tile[(nl + 1) * 68 + cl] = f2bf(v.y);
    tile[(nl + 2) * 68 + cl] = f2bf(v.z);
    tile[(nl + 3) * 68 + cl] = f2bf(v.w);
  }
  __syncthreads();
  u16* ob = xbT + (size_t)(b * NN + n0) * NC + c0;
#pragma unroll
  for (int i = 0; i < 4; ++i) {
    int e = t + i * 256;
    int nl = e >> 4;            // 0..63
    int cl = (e & 15) * 4;      // 0..60
    ushort4 pv = *(const ushort4*)&tile[nl * 68 + cl];
    *(ushort4*)(ob + (size_t)nl * NC + cl) = pv;
  }
}

// ---------------------------------------------------------------------------
// Kernel 2: q[b][n] = sum_c W[0][c] * x[b][c][n]   (fp32, coalesced over n)
// ---------------------------------------------------------------------------
__global__ __launch_bounds__(256) void k_q(const float* __restrict__ x,
                                           const float* __restrict__ W,
                                           float* __restrict__ q) {
  const int b = blockIdx.y;
  const int n = blockIdx.x * 256 + threadIdx.x;
  const float* xp = x + (size_t)b * NC * NN + n;
  float acc = 0.f;
#pragma unroll 16
  for (int c = 0; c < NC; ++c) acc += W[c] * xp[(size_t)c * NN];
  q[b * NN + n] = acc;
}

// ---------------------------------------------------------------------------
// Kernel 3: s[b][n] = softmax over n of q[b][n]   (one block per batch)
// ---------------------------------------------------------------------------
__global__ __launch_bounds__(256) void k_softmax(const float* __restrict__ q,
                                                 float* __restrict__ s) {
  __shared__ float red[256];
  const int b = blockIdx.x, t = threadIdx.x;
  const float* qb = q + b * NN;
  float v[16];
  float m = -3.4e38f;
#pragma unroll
  for (int i = 0; i < 16; ++i) { v[i] = qb[t + i * 256]; m = fmaxf(m, v[i]); }
  red[t] = m;
  __syncthreads();
  for (int off = 128; off > 0; off >>= 1) {
    if (t < off) red[t] = fmaxf(red[t], red[t + off]);
    __syncthreads();
  }
  const float M = red[0];
  __syncthreads();
  float sum = 0.f;
#pragma unroll
  for (int i = 0; i < 16; ++i) { v[i] = __expf(v[i] - M); sum += v[i]; }
  red[t] = sum;
  __syncthreads();
  for (int off = 128; off > 0; off >>= 1) {
    if (t < off) red[t] += red[t + off];
    __syncthreads();
  }
  const float inv = 1.f / red[0];
  float* sb = s + b * NN;
#pragma unroll
  for (int i = 0; i < 16; ++i) sb[t + i * 256] = v[i] * inv;
}

// ---------------------------------------------------------------------------
// Kernel 4: xs[b][c] = sum_n x[b][c][n] * s[b][n]  (fp32, block per (b,c))
// ---------------------------------------------------------------------------
__global__ __launch_bounds__(256) void k_xs(const float* __restrict__ x,
                                            const float* __restrict__ s,
                                            float* __restrict__ xs) {
  __shared__ float red[256];
  const int c = blockIdx.x, b = blockIdx.y, t = threadIdx.x;
  const float* xp = x + (size_t)(b * NC + c) * NN;
  const float* sp = s + b * NN;
  float acc = 0.f;
#pragma unroll
  for (int i = 0; i < 16; ++i) { int n = t + i * 256; acc += xp[n] * sp[n]; }
  red[t] = acc;
  __syncthreads();
  for (int off = 128; off > 0; off >>= 1) {
    if (t < off) red[t] += red[t + off];
    __syncthreads();
  }
  if (t == 0) xs[b * NC + c] = red[0];
}

// ---------------------------------------------------------------------------
// Kernel 5: ctx[b][d] = sum_c W[1+d][c] * xs[b][c]  (fp32, block per batch)
// ---------------------------------------------------------------------------
__global__ __launch_bounds__(256) void k_ctx(const float* __restrict__ W,
                                             const float* __restrict__ xs,
                                             float* __restrict__ ctx) {
  __shared__ float sx[NC];
  const int b = blockIdx.x, d = threadIdx.x;
  sx[d] = xs[b * NC + d];
  __syncthreads();
  const float* wk = W + (size_t)(1 + d) * NC;
  float acc = 0.f;
#pragma unroll 4
  for (int c = 0; c < NC; ++c) acc += wk[c] * sx[c];
  ctx[b * NC + d] = acc;
}

// ---------------------------------------------------------------------------
// Kernel 6: wvb[d][c] = bf16(W[1+D+d][c])
// ---------------------------------------------------------------------------
__global__ __launch_bounds__(256) void k_castwv(const float* __restrict__ W,
                                                u16* __restrict__ wvb) {
  const int i = (blockIdx.x * 256 + threadIdx.x) * 4;
  const float4 v = *(const float4*)(W + (size_t)(1 + ND) * NC + i);
  ushort4 o;
  o.x = f2bf(v.x); o.y = f2bf(v.y); o.z = f2bf(v.z); o.w = f2bf(v.w);
  *(ushort4*)(wvb + i) = o;
}

// ---------------------------------------------------------------------------
// Kernel 7: out[b][d][n] = relu( (Wv @ x)[d][n] ) * ctx[b][d]
// bf16 MFMA 16x16x32, 128x128 block tile, BK=32, 4 waves (2x2 of 64x64),
// global_load_lds width-16 staging (m97 structure).
//   A = Wv (d x c), LDS As[128][32] k-contiguous
//   B = xbT (n x c rows = x^T), LDS Bs[128][32] k-contiguous
// Fragment maps (verified m89/m91): A[m=lane&15][k=quad*8+j],
// B[k=quad*8+j][n=lane&15], D[m=quad*4+r][n=lane&15].
// ---------------------------------------------------------------------------
#define BM 128
#define BN 128
#define BK 32

__global__ __launch_bounds__(256) void k_gemm(const u16* __restrict__ xbT,
                                              const u16* __restrict__ wvb,
                                              const float* __restrict__ ctx,
                                              float* __restrict__ out) {
  __shared__ __align__(16) u16 As[BM * BK];
  __shared__ __align__(16) u16 Bs[BN * BK];
  const int t = threadIdx.x;
  const int b = blockIdx.z;
  const int d0 = blockIdx.y * BM;
  const int n0 = blockIdx.x * BN;
  const int lane = t & 63, w = t >> 6;
  const int wd = (w & 1) * 64, wn = (w >> 1) * 64;
  const int quad = lane >> 4, l15 = lane & 15;

  f32x4 acc[4][4];
#pragma unroll
  for (int mi = 0; mi < 4; ++mi)
#pragma unroll
    for (int ni = 0; ni < 4; ++ni)
      acc[mi][ni] = (f32x4){0.f, 0.f, 0.f, 0.f};

  const int row0 = t >> 2;       // 0..63 (LDS row this thread stages)
  const int qc8 = (t & 3) * 8;   // element offset of its 16B chunk in the row

  const u16* gA = wvb + (size_t)(d0 + row0) * NC + qc8;
  const u16* gB = xbT + (size_t)(b * NN + n0 + row0) * NC + qc8;
  u16* lA = &As[row0 * BK + qc8];
  u16* lB = &Bs[row0 * BK + qc8];

  for (int kk = 0; kk < NC; kk += BK) {
    __syncthreads();  // previous iteration's LDS reads complete
#pragma unroll
    for (int i = 0; i < 2; ++i) {
      __builtin_amdgcn_global_load_lds(
          (const __attribute__((address_space(1))) u32*)(gA + kk + (size_t)(64 * i) * NC),
          (__attribute__((address_space(3))) u32*)(lA + 64 * i * BK), 16, 0, 0);
      __builtin_amdgcn_global_load_lds(
          (const __attribute__((address_space(1))) u32*)(gB + kk + (size_t)(64 * i) * NC),
          (__attribute__((address_space(3))) u32*)(lB + 64 * i * BK), 16, 0, 0);
    }
    __syncthreads();  // compiler drains vmcnt(0) before barrier

    short8 af[4], bfr[4];
#pragma unroll
    for (int mi = 0; mi < 4; ++mi)
      af[mi] = *(const short8*)&As[(wd + mi * 16 + l15) * BK + quad * 8];
#pragma unroll
    for (int ni = 0; ni < 4; ++ni)
      bfr[ni] = *(const short8*)&Bs[(wn + ni * 16 + l15) * BK + quad * 8];
#pragma unroll
    for (int mi = 0; mi < 4; ++mi)
#pragma unroll
      for (int ni = 0; ni < 4; ++ni)
        acc[mi][ni] = __builtin_amdgcn_mfma_f32_16x16x32_bf16(af[mi], bfr[ni],
                                                              acc[mi][ni], 0, 0, 0);
  }

#pragma unroll
  for (int mi = 0; mi < 4; ++mi) {
#pragma unroll
    for (int r = 0; r < 4; ++r) {
      const int d = d0 + wd + mi * 16 + quad * 4 + r;
      const float cx = ctx[b * NC + d];
      float* op = out + (size_t)(b * NC + d) * NN + n0 + wn + l15;
#pragma unroll
      for (int ni = 0; ni < 4; ++ni) {
        float v = acc[mi][ni][r];
        op[ni * 16] = fmaxf(v, 0.f) * cx;
      }
    }
  }
}

// ---------------------------------------------------------------------------
extern "C" void kernel_launch(void* const* d_in, const int* in_sizes, int n_in,
                              void* d_out, int out_size, void* d_ws, size_t ws_size,
                              hipStream_t stream) {
  const float* x = (const float*)d_in[0];
  const float* W = (const float*)d_in[1];
  float* out = (float*)d_out;

  char* ws = (char*)d_ws;
  u16* xbT   = (u16*)ws;                                  // 33,554,432 B
  float* q   = (float*)(ws + 33554432);                   //    262,144 B
  float* s   = (float*)(ws + 33554432 + 262144);          //    262,144 B
  float* xs  = (float*)(ws + 33554432 + 524288);          //     16,384 B
  float* ctx = (float*)(ws + 33554432 + 540672);          //     16,384 B
  u16* wvb   = (u16*)(ws + 33554432 + 557056);            //    131,072 B

  k_cast_transpose<<<dim3(64, 4, 16), 256, 0, stream>>>(x, xbT);
  k_q<<<dim3(16, 16), 256, 0, stream>>>(x, W, q);
  k_softmax<<<16, 256, 0, stream>>>(q, s);
  k_xs<<<dim3(256, 16), 256, 0, stream>>>(x, s, xs);
  k_ctx<<<16, 256, 0, stream>>>(W, xs, ctx);
  k_castwv<<<64, 256, 0, stream>>>(W, wvb);
  k_gemm<<<dim3(32, 2, 16), 256, 0, stream>>>(xbT, wvb, ctx, out);
}

// Round 2
// 154.152 us; speedup vs baseline: 1.1401x; 1.1401x over previous
//
#include <hip/hip_runtime.h>
#include <cstdint>
#include <cstddef>

#define NB 16
#define NC 256
#define NN 4096
#define ND 256

typedef unsigned short u16;
typedef unsigned int u32;

typedef __attribute__((ext_vector_type(8))) short short8;
typedef __attribute__((ext_vector_type(4))) float f32x4;

__device__ __forceinline__ u16 f2bf(float f) {
  union { float f; u32 u; } v; v.f = f;
  u32 r = v.u + 0x7FFFu + ((v.u >> 16) & 1u);
  return (u16)(r >> 16);
}
__device__ __forceinline__ float bf2f(u16 h) {
  union { u32 u; float f; } v; v.u = ((u32)h) << 16; return v.f;
}

// ---------------------------------------------------------------------------
// Kernel 0: zero q (65536 floats) and xs (4096 floats) for atomic accumulation
// ---------------------------------------------------------------------------
__global__ __launch_bounds__(256) void k_zero(float* __restrict__ q,
                                              float* __restrict__ xs) {
  const int i = blockIdx.x * 256 + threadIdx.x;   // 0..69631
  if (i < NB * NN) q[i] = 0.f;
  else xs[i - NB * NN] = 0.f;
}

// ---------------------------------------------------------------------------
// Kernel 1: cast x (fp32 [b][c][n]) -> xbT (bf16 [b][n][c]) via LDS transpose,
// FUSED with partial q[b][n] += sum_c W[0][c]*x[b][c][n] (atomicAdd, 4-way).
// ---------------------------------------------------------------------------
__global__ __launch_bounds__(256) void k_cast_transpose_q(const float* __restrict__ x,
                                                          const float* __restrict__ W,
                                                          u16* __restrict__ xbT,
                                                          float* __restrict__ q) {
  __shared__ __align__(16) u16 tile[64 * 68];
  __shared__ float qred[16 * 64];
  const int t = threadIdx.x;
  const int b = blockIdx.z, c0 = blockIdx.y * 64, n0 = blockIdx.x * 64;
  const float* xb = x + (size_t)(b * NC + c0) * NN + n0;
  const int nl = (t & 15) * 4;
  float qacc[4] = {0.f, 0.f, 0.f, 0.f};
#pragma unroll
  for (int i = 0; i < 4; ++i) {
    int cl = (t >> 4) + i * 16;   // 0..63
    float4 v = *(const float4*)(xb + (size_t)cl * NN + nl);
    const float wq = W[c0 + cl];
    qacc[0] += wq * v.x; qacc[1] += wq * v.y;
    qacc[2] += wq * v.z; qacc[3] += wq * v.w;
    tile[(nl + 0) * 68 + cl] = f2bf(v.x);
    tile[(nl + 1) * 68 + cl] = f2bf(v.y);
    tile[(nl + 2) * 68 + cl] = f2bf(v.z);
    tile[(nl + 3) * 68 + cl] = f2bf(v.w);
  }
#pragma unroll
  for (int j = 0; j < 4; ++j) qred[(t >> 4) * 64 + nl + j] = qacc[j];
  __syncthreads();
  u16* ob = xbT + (size_t)(b * NN + n0) * NC + c0;
#pragma unroll
  for (int i = 0; i < 4; ++i) {
    int e = t + i * 256;
    int rn = e >> 4;            // 0..63
    int rc = (e & 15) * 4;      // 0..60
    ushort4 pv = *(const ushort4*)&tile[rn * 68 + rc];
    *(ushort4*)(ob + (size_t)rn * NC + rc) = pv;
  }
  if (t < 64) {
    float s = 0.f;
#pragma unroll
    for (int k = 0; k < 16; ++k) s += qred[k * 64 + t];
    atomicAdd(&q[b * NN + n0 + t], s);
  }
}

// ---------------------------------------------------------------------------
// Kernel 2: s[b][n] = softmax over n of q[b][n]   (one block per batch)
// ---------------------------------------------------------------------------
__global__ __launch_bounds__(256) void k_softmax(const float* __restrict__ q,
                                                 float* __restrict__ s) {
  __shared__ float red[256];
  const int b = blockIdx.x, t = threadIdx.x;
  const float* qb = q + b * NN;
  float v[16];
  float m = -3.4e38f;
#pragma unroll
  for (int i = 0; i < 16; ++i) { v[i] = qb[t + i * 256]; m = fmaxf(m, v[i]); }
  red[t] = m;
  __syncthreads();
  for (int off = 128; off > 0; off >>= 1) {
    if (t < off) red[t] = fmaxf(red[t], red[t + off]);
    __syncthreads();
  }
  const float M = red[0];
  __syncthreads();
  float sum = 0.f;
#pragma unroll
  for (int i = 0; i < 16; ++i) { v[i] = __expf(v[i] - M); sum += v[i]; }
  red[t] = sum;
  __syncthreads();
  for (int off = 128; off > 0; off >>= 1) {
    if (t < off) red[t] += red[t + off];
    __syncthreads();
  }
  const float inv = 1.f / red[0];
  float* sb = s + b * NN;
#pragma unroll
  for (int i = 0; i < 16; ++i) sb[t + i * 256] = v[i] * inv;
}

// ---------------------------------------------------------------------------
// Kernel 3: xs[b][c] += sum_{n in chunk} xbT[b][n][c] * s[b][n]   (bf16 read)
// grid (32 n-chunks of 128, 16 b); thread t owns c=t; one atomicAdd per (b,c).
// ---------------------------------------------------------------------------
__global__ __launch_bounds__(256) void k_xs(const u16* __restrict__ xbT,
                                            const float* __restrict__ s,
                                            float* __restrict__ xs) {
  const int t = threadIdx.x;
  const int b = blockIdx.y, n0 = blockIdx.x * 128;
  const u16* xp = xbT + ((size_t)(b * NN + n0)) * NC + t;
  const float* sp = s + b * NN + n0;
  float acc = 0.f;
#pragma unroll 8
  for (int j = 0; j < 128; ++j) {
    acc += bf2f(xp[(size_t)j * NC]) * sp[j];
  }
  atomicAdd(&xs[b * NC + t], acc);
}

// ---------------------------------------------------------------------------
// Kernel 4: ctx[b][d] = sum_c W[1+d][c] * xs[b][c]  (fp32, block per batch)
// ---------------------------------------------------------------------------
__global__ __launch_bounds__(256) void k_ctx(const float* __restrict__ W,
                                             const float* __restrict__ xs,
                                             float* __restrict__ ctx) {
  __shared__ float sx[NC];
  const int b = blockIdx.x, d = threadIdx.x;
  sx[d] = xs[b * NC + d];
  __syncthreads();
  const float* wk = W + (size_t)(1 + d) * NC;
  float acc = 0.f;
#pragma unroll 4
  for (int c = 0; c < NC; ++c) acc += wk[c] * sx[c];
  ctx[b * NC + d] = acc;
}

// ---------------------------------------------------------------------------
// Kernel 5: wvb[d][c] = bf16(W[1+D+d][c])
// ---------------------------------------------------------------------------
__global__ __launch_bounds__(256) void k_castwv(const float* __restrict__ W,
                                                u16* __restrict__ wvb) {
  const int i = (blockIdx.x * 256 + threadIdx.x) * 4;
  const float4 v = *(const float4*)(W + (size_t)(1 + ND) * NC + i);
  ushort4 o;
  o.x = f2bf(v.x); o.y = f2bf(v.y); o.z = f2bf(v.z); o.w = f2bf(v.w);
  *(ushort4*)(wvb + i) = o;
}

// ---------------------------------------------------------------------------
// Kernel 6: out[b][d][n] = relu( (Wv @ x)[d][n] ) * ctx[b][d]
// bf16 MFMA 16x16x32, 128x128 tile, BK=64 (4 K-iters), 4 waves (2x2 of 64x64).
// LDS layout XOR-swizzled in 16B chunks: phys_chunk = chunk ^ (row & 7).
// Swizzle kills the 8-way ds_read_b128 bank conflict of the flat layout;
// global_load_lds staging stays legal because only the *global source* chunk
// is permuted per lane (each 8-lane group still covers one contiguous 128B row).
// ---------------------------------------------------------------------------
#define BM 128
#define BN 128
#define BK 64

__global__ __launch_bounds__(256) void k_gemm(const u16* __restrict__ xbT,
                                              const u16* __restrict__ wvb,
                                              const float* __restrict__ ctx,
                                              float* __restrict__ out) {
  __shared__ __align__(16) u16 As[BM * BK];   // 16 KB
  __shared__ __align__(16) u16 Bs[BN * BK];   // 16 KB
  const int t = threadIdx.x;
  const int b = blockIdx.z;
  const int d0 = blockIdx.y * BM;
  const int n0 = blockIdx.x * BN;
  const int lane = t & 63, w = t >> 6;
  const int wd = (w & 1) * 64, wn = (w >> 1) * 64;
  const int quad = lane >> 4, l15 = lane & 15;

  f32x4 acc[4][4];
#pragma unroll
  for (int mi = 0; mi < 4; ++mi)
#pragma unroll
    for (int ni = 0; ni < 4; ++ni)
      acc[mi][ni] = (f32x4){0.f, 0.f, 0.f, 0.f};

  // staging: thread t -> row (t>>3) (+32 per call-site), phys chunk t&7,
  // fetches logical chunk (t&7)^((t>>3)&7) of that row.
  const int rstg = t >> 3;                               // 0..31
  const int l8 = (((t & 7) ^ (rstg & 7))) * 8;           // logical u16 offset
  const u16* gA = wvb + (size_t)(d0 + rstg) * NC + l8;
  const u16* gB = xbT + (size_t)(b * NN + n0 + rstg) * NC + l8;
  const int ldst = 8 * t;                                // u16 offset in LDS

  // fragment-read phys chunks (row&7 == l15&7 for all mi/ni since wd,16*mi = 0 mod 8)
  const int pq0 = ((0 * 4 + quad) ^ (l15 & 7)) * 8;
  const int pq1 = ((1 * 4 + quad) ^ (l15 & 7)) * 8;

  for (int kk = 0; kk < NC; kk += BK) {
    __syncthreads();
#pragma unroll
    for (int i = 0; i < 4; ++i) {
      __builtin_amdgcn_global_load_lds(
          (const __attribute__((address_space(1))) u32*)(gA + kk + (size_t)(32 * i) * NC),
          (__attribute__((address_space(3))) u32*)(As + 2048 * i + ldst), 16, 0, 0);
      __builtin_amdgcn_global_load_lds(
          (const __attribute__((address_space(1))) u32*)(gB + kk + (size_t)(32 * i) * NC),
          (__attribute__((address_space(3))) u32*)(Bs + 2048 * i + ldst), 16, 0, 0);
    }
    __syncthreads();

#pragma unroll
    for (int kq = 0; kq < 2; ++kq) {
      const int pq = kq ? pq1 : pq0;
      short8 af[4], bfr[4];
#pragma unroll
      for (int mi = 0; mi < 4; ++mi)
        af[mi] = *(const short8*)&As[(wd + mi * 16 + l15) * BK + pq];
#pragma unroll
      for (int ni = 0; ni < 4; ++ni)
        bfr[ni] = *(const short8*)&Bs[(wn + ni * 16 + l15) * BK + pq];
#pragma unroll
      for (int mi = 0; mi < 4; ++mi)
#pragma unroll
        for (int ni = 0; ni < 4; ++ni)
          acc[mi][ni] = __builtin_amdgcn_mfma_f32_16x16x32_bf16(af[mi], bfr[ni],
                                                                acc[mi][ni], 0, 0, 0);
    }
  }

#pragma unroll
  for (int mi = 0; mi < 4; ++mi) {
#pragma unroll
    for (int r = 0; r < 4; ++r) {
      const int d = d0 + wd + mi * 16 + quad * 4 + r;
      const float cx = ctx[b * NC + d];
      float* op = out + (size_t)(b * NC + d) * NN + n0 + wn + l15;
#pragma unroll
      for (int ni = 0; ni < 4; ++ni) {
        float v = acc[mi][ni][r];
        op[ni * 16] = fmaxf(v, 0.f) * cx;
      }
    }
  }
}

// ---------------------------------------------------------------------------
extern "C" void kernel_launch(void* const* d_in, const int* in_sizes, int n_in,
                              void* d_out, int out_size, void* d_ws, size_t ws_size,
                              hipStream_t stream) {
  const float* x = (const float*)d_in[0];
  const float* W = (const float*)d_in[1];
  float* out = (float*)d_out;

  char* ws = (char*)d_ws;
  u16* xbT   = (u16*)ws;                                  // 33,554,432 B
  float* q   = (float*)(ws + 33554432);                   //    262,144 B
  float* s   = (float*)(ws + 33554432 + 262144);          //    262,144 B
  float* xs  = (float*)(ws + 33554432 + 524288);          //     16,384 B
  float* ctx = (float*)(ws + 33554432 + 540672);          //     16,384 B
  u16* wvb   = (u16*)(ws + 33554432 + 557056);            //    131,072 B

  k_zero<<<272, 256, 0, stream>>>(q, xs);
  k_cast_transpose_q<<<dim3(64, 4, 16), 256, 0, stream>>>(x, W, xbT, q);
  k_softmax<<<16, 256, 0, stream>>>(q, s);
  k_xs<<<dim3(32, 16), 256, 0, stream>>>(xbT, s, xs);
  k_ctx<<<16, 256, 0, stream>>>(W, xs, ctx);
  k_castwv<<<64, 256, 0, stream>>>(W, wvb);
  k_gemm<<<dim3(32, 2, 16), 256, 0, stream>>>(xbT, wvb, ctx, out);
}